// Round 19
// baseline (451.088 us; speedup 1.0000x reference)
//
#include <hip/hip_runtime.h>

#define DI __device__ __forceinline__
DI float silu_f(float x){ return x * (1.0f/(1.0f+__expf(-x))); }

template<int X> struct LOG2 { static constexpr int v = 1 + LOG2<X/2>::v; };
template<> struct LOG2<1> { static constexpr int v = 0; };

// ---------------------------------------------------------------------------
// Direct conv (r17/r18 core). G FROZEN (VQ argmin rounding). TOW row-band.
// r19: FG>0 fuses the G-partial reduce of the INPUT tensor into si staging:
// staged = silu(sum_g p[g*fstr+off] + fb[ch]) with g ascending -> identical
// expression+order as reduce_k -> bit-identical staged values (vq precedent).
// ---------------------------------------------------------------------------
template<int KH,int KW,int STRIDE,int PAD,int CIN,int COUT,int NPIX,
         bool ACT,bool BIAS,int G,int CS,int TOW,int FG>
__global__ __launch_bounds__(256) void conv_k(
    const float* __restrict__ in, const float* __restrict__ w,
    const float* __restrict__ bias, float* __restrict__ out,
    const float* __restrict__ fb, size_t fstr,
    int N,int H,int W,int OH,int OW)
{
  constexpr int CLEN = CIN/G;
  constexpr int COB  = COUT/CS;
  constexpr int COQ  = COB/4;
  constexpr int GSH  = LOG2<G>::v;
  constexpr int CSH  = LOG2<CS>::v;
  constexpr int TAPF = CLEN*COB;
  constexpr bool SALL = (KH*KW*TAPF*4) <= 47*1024;
  constexpr int NTAP = SALL ? KH*KW : KW;
  static_assert(CLEN==3 || (CLEN%4)==0, "ci");
  static_assert(FG==0 || (TOW>0 && CLEN!=3), "fg");
  __shared__ float sw[NTAP*TAPF];
  constexpr int SPAN = (TOW>0) ? (TOW-1)*STRIDE + KW : 1;
  constexpr int ROWS = (TOW>0) ? ((256/COQ)*NPIX)/TOW : 1;
  constexpr int CQ4  = (TOW>0 && CLEN!=3) ? CLEN/4 : 1;
  constexpr int SI_F = (TOW==0) ? 1 : (CLEN==3 ? ROWS*SPAN*3 : ROWS*CQ4*SPAN*4);
  __shared__ float si[SI_F];
  static_assert(TOW==0 || NPIX<=2, "tow npix");
  static_assert(TOW==0 || ((256/COQ)*NPIX) % TOW == 0, "rows");

  const int g  = blockIdx.x & (G-1);
  const int cs = (blockIdx.x >> GSH) & (CS-1);
  const int bx = blockIdx.x >> (GSH+CSH);
  const int total = N*OH*OW;
  if (G>1) out += (size_t)g * total * COUT;
  const int ci_off  = g*CLEN;
  const int co_base = cs*COB;

  int idx = bx*256 + (int)threadIdx.x;
  int cq = idx % COQ;
  int pg = idx / COQ;
  int co = cq*4;
  int gco = co_base + co;
  int p0 = pg*NPIX;

  float acc[NPIX][4] = {};
  int iy0[NPIX], ix0[NPIX]; const float* base[NPIX]; bool pv[NPIX];
#pragma unroll
  for (int t=0;t<NPIX;t++){
    int p=p0+t; pv[t]=(p<total); int pp=pv[t]?p:0;
    int ox=pp%OW; int r=pp/OW; int oy=r%OH; int n=r/OH;
    iy0[t]=oy*STRIDE-PAD; ix0[t]=ox*STRIDE-PAD;
    base[t]=in+(size_t)n*H*W*CIN + ci_off;
  }

  auto stage = [&](int tap0){
    constexpr int TQ = TAPF/4;
    constexpr int V  = NTAP*TQ;
    for (int v=threadIdx.x; v<V; v+=256){
      int tap = v / TQ; int rem = v - tap*TQ;
      float4 q;
      if constexpr (CS==1){
        const float4* src = (const float4*)(w + ((size_t)(tap0+tap)*CIN + ci_off)*COUT);
        q = src[rem];
      } else if constexpr (CLEN==3){
        int ci = rem / (COB/4); int r2 = rem - ci*(COB/4);
        q = *(const float4*)(w + ((size_t)(tap0+tap)*CIN + ci)*COUT
                               + co_base + r2*4);
      } else {
        int ci = rem / (COB/4); int r2 = rem - ci*(COB/4);
        q = *(const float4*)(w + ((size_t)(tap0+tap)*CIN + ci_off + ci)*COUT
                               + co_base + r2*4);
      }
      *(float4*)(sw + (size_t)tap*TAPF + rem*4) = q;
    }
  };

  if constexpr (SALL){
    stage(0);
    __syncthreads();
  }

  if constexpr (TOW>0){
    const int pb0 = bx * ((256/COQ)*NPIX);
    const int r0  = pb0 / TOW;
    const int oy0 = r0 % OH;
    const int n0  = r0 / OH;
    int myrow[NPIX], oxl[NPIX];
#pragma unroll
    for (int t=0;t<NPIX;t++){
      int pl = p0 + t - pb0;
      myrow[t] = pl / TOW;
      oxl[t]   = pl - myrow[t]*TOW;
    }

    for (int ky=0; ky<KH; ky++){
      __syncthreads();
      if constexpr (!SALL) stage(ky*KW);
      if constexpr (CLEN==3){
        constexpr int INS = ROWS*SPAN;
        for (int v=(int)threadIdx.x; v<INS; v+=256){
          int r  = v / SPAN;
          int ixo= v - r*SPAN;
          int iy = (oy0+r)*STRIDE - PAD + ky;
          int ix = ixo - PAD;
          bool ok = iy>=0 && iy<H && ix>=0 && ix<W;
          const float* ip = in + ((size_t)(n0*H+iy)*W + ix)*CIN;
          si[v*3+0] = ok?ip[0]:0.f;
          si[v*3+1] = ok?ip[1]:0.f;
          si[v*3+2] = ok?ip[2]:0.f;
        }
      } else {
        constexpr int INQ = ROWS*CQ4*SPAN;
        for (int v=(int)threadIdx.x; v<INQ; v+=256){
          int r  = v / (CQ4*SPAN);
          int rm = v - r*(CQ4*SPAN);
          int q  = rm / SPAN;
          int ixo= rm - q*SPAN;
          int iy = (oy0+r)*STRIDE - PAD + ky;
          int ix = ixo - PAD;
          bool ok = iy>=0 && iy<H && ix>=0 && ix<W;
          float4 val = make_float4(0.f,0.f,0.f,0.f);
          if (ok){
            size_t off = ((size_t)(n0*H+iy)*W + ix)*CIN + ci_off + q*4;
            if constexpr (FG>0){
              float a[4]; *(float4*)a = *(const float4*)(in + off);
#pragma unroll
              for (int g2=1; g2<FG; g2++){
                float b[4]; *(float4*)b = *(const float4*)(in + (size_t)g2*fstr + off);
#pragma unroll
                for (int j=0;j<4;j++) a[j]+=b[j];
              }
              float bb[4]; *(float4*)bb = *(const float4*)(fb + ci_off + q*4);
#pragma unroll
              for (int j=0;j<4;j++) a[j] = silu_f(a[j]+bb[j]);
              val = *(float4*)a;
            } else {
              val = *(const float4*)(in + off);
            }
          }
          *(float4*)&si[(size_t)v*4] = val;
        }
      }
      __syncthreads();
      const float* swr = SALL ? sw + (size_t)ky*KW*TAPF : sw;
      for (int kx=0; kx<KW; kx++){
        const float* swt = swr + (size_t)kx*TAPF;
        if constexpr (CLEN==3){
          float wv[3][4];
          *(float4*)wv[0]=*(const float4*)(swt + 0*COB + co);
          *(float4*)wv[1]=*(const float4*)(swt + 1*COB + co);
          *(float4*)wv[2]=*(const float4*)(swt + 2*COB + co);
#pragma unroll
          for (int t=0;t<NPIX;t++){
            const float* sp = &si[(size_t)(myrow[t]*SPAN + oxl[t]*STRIDE + kx)*3];
            float v0=sp[0], v1=sp[1], v2=sp[2];
#pragma unroll
            for (int j=0;j<4;j++)
              acc[t][j]=fmaf(v0,wv[0][j],fmaf(v1,wv[1][j],fmaf(v2,wv[2][j],acc[t][j])));
          }
        } else {
#pragma unroll 2
          for (int c=0; c<CQ4; c++){
            float wv[4][4];
#pragma unroll
            for (int r=0;r<4;r++)
              *(float4*)wv[r] = *(const float4*)(swt + (c*4+r)*COB + co);
#pragma unroll
            for (int t=0;t<NPIX;t++){
              float va[4];
              *(float4*)va = *(const float4*)&si[(size_t)((myrow[t]*CQ4 + c)*SPAN + oxl[t]*STRIDE + kx)*4];
#pragma unroll
              for (int r=0;r<4;r++)
#pragma unroll
                for (int j=0;j<4;j++)
                  acc[t][j]=fmaf(va[r],wv[r][j],acc[t][j]);
            }
          }
        }
      }
    }
  } else {
    for (int ky=0; ky<KH; ky++){
      if constexpr (!SALL){
        __syncthreads();
        stage(ky*KW);
        __syncthreads();
      }
      const float* swr = SALL ? sw + (size_t)ky*KW*TAPF : sw;
      for (int kx=0; kx<KW; kx++){
        const float* swt = swr + (size_t)kx*TAPF;
        const float* ip[NPIX]; bool ok[NPIX];
#pragma unroll
        for (int t=0;t<NPIX;t++){
          int iy=iy0[t]+ky, ix=ix0[t]+kx;
          ok[t]=pv[t] && iy>=0 && iy<H && ix>=0 && ix<W;
          ip[t]=base[t]+(size_t)(iy*W+ix)*CIN;
        }
        if constexpr (CLEN==3){
          float wv[3][4];
          *(float4*)wv[0]=*(const float4*)(swt + 0*COB + co);
          *(float4*)wv[1]=*(const float4*)(swt + 1*COB + co);
          *(float4*)wv[2]=*(const float4*)(swt + 2*COB + co);
#pragma unroll
          for (int t=0;t<NPIX;t++){
            float v0=ok[t]?ip[t][0]:0.f;
            float v1=ok[t]?ip[t][1]:0.f;
            float v2=ok[t]?ip[t][2]:0.f;
#pragma unroll
            for (int j=0;j<4;j++)
              acc[t][j]=fmaf(v0,wv[0][j],fmaf(v1,wv[1][j],fmaf(v2,wv[2][j],acc[t][j])));
          }
        } else {
#pragma unroll 2
          for (int ci=0; ci<CLEN; ci+=4){
            float wv[4][4];
#pragma unroll
            for (int r=0;r<4;r++)
              *(float4*)wv[r] = *(const float4*)(swt + (ci+r)*COB + co);
#pragma unroll
            for (int t=0;t<NPIX;t++){
              float va[4];
              *(float4*)va = ok[t] ? *(const float4*)(ip[t]+ci)
                                   : make_float4(0.f,0.f,0.f,0.f);
#pragma unroll
              for (int r=0;r<4;r++)
#pragma unroll
                for (int j=0;j<4;j++)
                  acc[t][j]=fmaf(va[r],wv[r][j],acc[t][j]);
            }
          }
        }
      }
    }
  }

  float bv[4]={0.f,0.f,0.f,0.f};
  if constexpr (BIAS) *(float4*)bv = *(const float4*)(bias+gco);
#pragma unroll
  for (int t=0;t<NPIX;t++) if (pv[t]){
    float o[4];
#pragma unroll
    for (int j=0;j<4;j++){
      float v = acc[t][j]+bv[j];
      o[j] = ACT ? silu_f(v) : v;
    }
    *(float4*)(out + (size_t)(p0+t)*COUT + gco) = *(float4*)o;
  }
}

// ---------------------------------------------------------------------------
// conv_transpose 5x5 s2 SAME, single-stage row-band (r18-proven) + r19 FG
// fused input reduce (same order as reduce_k -> bit-identical).
// ---------------------------------------------------------------------------
template<int CIN,int COUT,int NPIX,int G,int CS,int IW,bool DIRECT,int FG>
__global__ __launch_bounds__(256) void tconv_rb(
    const float* __restrict__ in, const float* __restrict__ w,
    const float* __restrict__ bias, float* __restrict__ out,
    const float* __restrict__ fb, size_t fstr,
    int N,int H,int W,int OH,int OW)
{
  constexpr int CLEN = CIN/G;
  constexpr int COB  = COUT/CS;
  constexpr int COQ  = COB/4;
  constexpr int GSH  = LOG2<G>::v;
  constexpr int CSH  = LOG2<CS>::v;
  constexpr int TAPF = CLEN*COB;
  constexpr int PPB  = (256/COQ)*NPIX;
  static_assert(PPB % IW == 0, "whole rows");
  constexpr int ROWS_O = PPB/IW;
  constexpr int NRI  = ROWS_O + 2;
  constexpr int SPAN = IW + 2;
  constexpr int CQ4  = CLEN/4;
  __shared__ float sw[9*TAPF];
  __shared__ float si[NRI*CQ4*SPAN*4];

  const int par = blockIdx.x & 3;
  const int py = par>>1, px = par&1;
  const int g  = (blockIdx.x>>2) & (G-1);
  const int cs = (blockIdx.x>>(2+GSH)) & (CS-1);
  const int bx = blockIdx.x >> (2+GSH+CSH);
  const int NKY = py?3:2, NKX = px?3:2;
  const int OHh = OH>>1;
  if (G>1) out += (size_t)g * (size_t)N*OH*OW*COUT;
  const int co_base = cs*COB;

  const int tid = (int)threadIdx.x;
  int idx = bx*256 + tid;
  int cq = idx % COQ;
  int pg = idx / COQ;
  int co = cq*4;
  int p0 = pg*NPIX;
  const int pb0 = bx*PPB;
  const int R0  = pb0 / IW;
  const int oy0 = R0 % OHh;
  const int n0  = R0 / OHh;

  int myrow[NPIX], xx[NPIX];
#pragma unroll
  for (int t=0;t<NPIX;t++){
    int lp = p0 + t - pb0;
    myrow[t] = lp / IW;
    xx[t]    = lp - myrow[t]*IW;
  }

  {
    constexpr int TQ = TAPF/4;
    const int V = NKY*NKX*TQ;
    for (int v=tid; v<V; v+=256){
      int tap = v / TQ; int rem = v - tap*TQ;
      int j = tap / NKX, i = tap - j*NKX;
      int ky = 2*j + (py?0:1), kx = 2*i + (px?0:1);
      int ci = rem / (COB/4); int r2 = rem - ci*(COB/4);
      float4 q = *(const float4*)(w + ((size_t)(ky*5+kx)*CIN + g*CLEN + ci)*COUT
                                    + co_base + r2*4);
      *(float4*)(sw + (size_t)(j*3+i)*TAPF + rem*4) = q;
    }
  }
  {
    constexpr int INQ = NRI*CQ4*SPAN;
    for (int v=tid; v<INQ; v+=256){
      int r  = v / (CQ4*SPAN);
      int rm = v - r*(CQ4*SPAN);
      int q  = rm / SPAN;
      int cc = rm - q*SPAN;
      int iy = oy0 - 1 + r;
      int ix = cc - 1;
      bool ok = iy>=0 && iy<H && ix>=0 && ix<W;
      float4 val = make_float4(0.f,0.f,0.f,0.f);
      if (ok){
        size_t off = ((size_t)(n0*H+iy)*W + ix)*CIN + g*CLEN + q*4;
        if constexpr (FG>0){
          float a[4]; *(float4*)a = *(const float4*)(in + off);
#pragma unroll
          for (int g2=1; g2<FG; g2++){
            float b[4]; *(float4*)b = *(const float4*)(in + (size_t)g2*fstr + off);
#pragma unroll
            for (int j=0;j<4;j++) a[j]+=b[j];
          }
          float bb[4]; *(float4*)bb = *(const float4*)(fb + g*CLEN + q*4);
#pragma unroll
          for (int j=0;j<4;j++) a[j] = silu_f(a[j]+bb[j]);
          val = *(float4*)a;
        } else {
          val = *(const float4*)(in + off);
        }
      }
      *(float4*)&si[(size_t)v*4] = val;
    }
  }
  __syncthreads();

  float acc[NPIX][4] = {};
  for (int j=0;j<NKY;j++){
    for (int i=0;i<NKX;i++){
      const float* swt = sw + (size_t)(j*3+i)*TAPF;
#pragma unroll 2
      for (int c=0;c<CQ4;c++){
        float wv[4][4];
#pragma unroll
        for (int r=0;r<4;r++)
          *(float4*)wv[r] = *(const float4*)(swt + (c*4+r)*COB + co);
#pragma unroll
        for (int t=0;t<NPIX;t++){
          float va[4];
          *(float4*)va = *(const float4*)&si[(size_t)(((myrow[t]+j)*CQ4 + c)*SPAN + (xx[t]+i))*4];
#pragma unroll
          for (int r=0;r<4;r++)
#pragma unroll
            for (int jj=0;jj<4;jj++)
              acc[t][jj]=fmaf(va[r],wv[r][jj],acc[t][jj]);
        }
      }
    }
  }

  float bv[4]={0.f,0.f,0.f,0.f};
  if constexpr (DIRECT) *(float4*)bv = *(const float4*)(bias+co_base+co);
#pragma unroll
  for (int t=0;t<NPIX;t++){
    float o[4];
#pragma unroll
    for (int jj=0;jj<4;jj++){
      float v = acc[t][jj]+bv[jj];
      o[jj] = DIRECT ? silu_f(v) : v;
    }
    *(float4*)(out + (((size_t)n0*OH + (2*(oy0+myrow[t])+py))*OW + (2*xx[t]+px))*COUT + co_base+co) = *(float4*)o;
  }
}

// ---------------------------------------------------------------------------
// VQ fused with conv3c 2-partial reduction + bias (round-2 EXACT — FROZEN).
// ---------------------------------------------------------------------------
__global__ __launch_bounds__(256) void vq_k(
    const float* __restrict__ p, const float* __restrict__ bias,
    const float* __restrict__ cb, float* __restrict__ q, int NLat)
{
  __shared__ float slat[4][128];
  int wave = threadIdx.x >> 6;
  int lane = threadIdx.x & 63;
  int l = blockIdx.x*4 + wave;
  if (l >= NLat) return;
  const float* p0 = p + (size_t)l*128;
  const float* p1 = p0 + (size_t)NLat*128;
  slat[wave][lane]    = p0[lane]    + p1[lane]    + bias[lane];
  slat[wave][lane+64] = p0[lane+64] + p1[lane+64] + bias[lane+64];

  float bestd = INFINITY; int besti = 0;
  for (int c0=0;c0<256;c0+=64){
    int c = c0 + lane;
    const float* cp = cb + (size_t)c*128;
    float d = 0.f;
#pragma unroll 8
    for (int k=0;k<128;k+=4){
      float4 cv = *reinterpret_cast<const float4*>(cp+k);
      float d0 = slat[wave][k+0]-cv.x;
      float d1 = slat[wave][k+1]-cv.y;
      float d2 = slat[wave][k+2]-cv.z;
      float d3 = slat[wave][k+3]-cv.w;
      d += d0*d0; d += d1*d1; d += d2*d2; d += d3*d3;
    }
    if (d < bestd) { bestd = d; besti = c; }
  }
  for (int off=32; off; off>>=1){
    float od = __shfl_down(bestd, off);
    int   oi = __shfl_down(besti, off);
    if (od < bestd || (od == bestd && oi < besti)) { bestd=od; besti=oi; }
  }
  besti = __shfl(besti, 0);
  const float* cp = cb + (size_t)besti*128;
  float* qp = q + (size_t)l*128;
  qp[lane]    = cp[lane];
  qp[lane+64] = cp[lane+64];
}

// ---------------------------------------------------------------------------
// Final 3x3 conv 32->3 split over ky rows (g = blockIdx%3). Writes partials.
// ---------------------------------------------------------------------------
__global__ __launch_bounds__(256) void conv_last_k(
    const float* __restrict__ in, const float* __restrict__ w,
    float* __restrict__ p, int N,int H,int W)
{
  int g = blockIdx.x % 3;
  int bx = blockIdx.x / 3;
  int pix = bx*256 + threadIdx.x;
  int total = N*H*W;
  if (pix>=total) return;
  int x = pix % W; int r = pix / W; int y = r % H; int n = r / H;
  float a0=0.f, a1=0.f, a2=0.f;
  int iy = y + g - 1;
  if (iy>=0 && iy<H){
    const float* base = in + ((size_t)n*H + iy)*W*32;
    for (int kx=0;kx<3;kx++){
      int ix=x+kx-1; if(ix<0||ix>=W) continue;
      const float* ip = base + (size_t)ix*32;
      const float* wp = w + (size_t)((g*3+kx)*32)*3;
#pragma unroll
      for (int ci=0;ci<32;ci+=4){
        float va[4]; *(float4*)va = *(const float4*)(ip+ci);
        float wv[12];
        *(float4*)(wv+0) = *(const float4*)(wp+ci*3+0);
        *(float4*)(wv+4) = *(const float4*)(wp+ci*3+4);
        *(float4*)(wv+8) = *(const float4*)(wp+ci*3+8);
#pragma unroll
        for (int r2=0;r2<4;r2++){
          a0 = fmaf(va[r2], wv[r2*3+0], a0);
          a1 = fmaf(va[r2], wv[r2*3+1], a1);
          a2 = fmaf(va[r2], wv[r2*3+2], a2);
        }
      }
    }
  }
  float* pp = p + (size_t)g*total*3 + (size_t)pix*3;
  pp[0]=a0; pp[1]=a1; pp[2]=a2;
}

__global__ __launch_bounds__(256) void reduce_last_k(
    const float* __restrict__ p, const float* __restrict__ bias,
    float* __restrict__ out, int n)
{
  int i = (blockIdx.x*256+threadIdx.x)*4;
  if (i>=n) return;
  float a[4]; *(float4*)a = *(const float4*)(p+i);
#pragma unroll
  for (int g=1; g<3; g++){
    float b[4]; *(float4*)b = *(const float4*)(p+(size_t)g*n+i);
#pragma unroll
    for (int j=0;j<4;j++) a[j]+=b[j];
  }
  float o[4];
#pragma unroll
  for (int j=0;j<4;j++) o[j] = a[j] + bias[(i+j)%3];
  *(float4*)(out+i) = *(float4*)o;
}

extern "C" void kernel_launch(void* const* d_in, const int* in_sizes, int n_in,
                              void* d_out, int out_size, void* d_ws, size_t ws_size,
                              hipStream_t stream) {
  const float* x    = (const float*)d_in[0];
  const float* k1   = (const float*)d_in[1];  const float* b1  = (const float*)d_in[2];
  const float* k1c  = (const float*)d_in[3];  const float* b1c = (const float*)d_in[4];
  const float* k2   = (const float*)d_in[5];  const float* b2  = (const float*)d_in[6];
  const float* k2c  = (const float*)d_in[7];  const float* b2c = (const float*)d_in[8];
  const float* k3   = (const float*)d_in[9];  const float* b3  = (const float*)d_in[10];
  const float* k3c  = (const float*)d_in[11]; const float* b3c = (const float*)d_in[12];
  const float* cb   = (const float*)d_in[13];
  const float* tk1  = (const float*)d_in[14]; const float* tb1  = (const float*)d_in[15];
  const float* tk1c = (const float*)d_in[16]; const float* tb1c = (const float*)d_in[17];
  const float* tk2  = (const float*)d_in[18]; const float* tb2  = (const float*)d_in[19];
  const float* tk2c = (const float*)d_in[20]; const float* tb2c = (const float*)d_in[21];
  const float* tk3  = (const float*)d_in[22]; const float* tb3  = (const float*)d_in[23];
  const float* tk3c = (const float*)d_in[24]; const float* tb3c = (const float*)d_in[25];
  float* out = (float*)d_out;

  float* S  = (float*)d_ws;
  float* W0 = S;                 // [0 .. 1M) floats
  float* W1 = S + 1048576;       // [1M .. 2M)
  float* PA = S + 2097152;       // conv2 partials   [2M..3M)
  float* PB = S + 3145728;       // conv3 partials   [3M..4M)
  float* PC = S + 2097152;       // conv3c partials  [2M..2.5M)
  float* PD = S + 2097152;       // tconv1 partials  [2M..4M)
  float* PE = S + 4194304;       // tk1c partials    [4M..5M)
  float* PF = S + 2097152;       // tconv2 partials  [2M..4M)
  float* PG = S + 2097152;       // tconv3 output    [2M..6M)
  dim3 blk(256);

  // ---- encoder: G-splits + fmaf/reduce order FROZEN (VQ argmin) ----
  conv_k<11,11,2,4,  3, 32,2,true ,true ,1,2,64,0><<< 512,blk,0,stream>>>(x,  k1,  b1,  W0, nullptr,0, 8,128,128,64,64);
  conv_k< 3, 3,1,1, 32, 32,2,true ,true ,1,2,64,0><<< 512,blk,0,stream>>>(W0, k1c, b1c, W1, nullptr,0, 8,64,64,64,64);
  conv_k<11,11,2,4, 32, 64,2,false,false,2,2,32,0><<< 512,blk,0,stream>>>(W1, k2,  nullptr, PA, nullptr,0, 8,64,64,32,32);
  // conv2c: fused reduce(conv2 partials,b2,silu) in staging -> direct out W0
  conv_k< 3, 3,1,1, 64, 64,1,true ,true ,1,2,32,2><<< 512,blk,0,stream>>>(PA, k2c, b2c, W0, b2,524288, 8,32,32,32,32);
  conv_k<11,11,2,4, 64,128,2,false,false,4,4,16,0><<< 512,blk,0,stream>>>(W0, k3,  nullptr, PB, nullptr,0, 8,32,32,16,16);
  // conv3c: fused reduce(conv3 partials,b3,silu) -> partials PC
  conv_k< 3, 3,1,1,128,128,1,false,false,2,4,16,4><<< 512,blk,0,stream>>>(PB, k3c, nullptr, PC, b3,262144, 8,16,16,16,16);
  // ---- VQ (FROZEN; reads conv3c partials) ----
  vq_k<<<512,blk,0,stream>>>(PC, b3c, cb, W1, 2048);
  // ---- decoder ----
  tconv_rb<128,64,1,4,2,16,false,0><<<2048,blk,0,stream>>>(W1, tk1, nullptr, PD, nullptr,0, 8,16,16,32,32);
  // tk1c: fused reduce(tconv1 partials,tb1,silu) -> partials PE
  conv_k< 3, 3,1,1, 64, 64,2,false,false,2,4,32,4><<< 512,blk,0,stream>>>(PD, tk1c, nullptr, PE, tb1,524288, 8,32,32,32,32);
  // tconv2: fused reduce(tk1c partials,tb1c,silu) -> partials PF
  tconv_rb< 64,32,1,2,1,32,false,2><<<2048,blk,0,stream>>>(PE, tk2, nullptr, PF, tb1c,524288, 8,32,32,64,64);
  // tk2c: fused reduce(tconv2 partials,tb2,silu) -> direct out W1
  conv_k< 3, 3,1,1, 32, 32,2,true ,true ,1,2,64,2><<< 512,blk,0,stream>>>(PF, tk2c, tb2c, W1, tb2,1048576, 8,64,64,64,64);
  tconv_rb< 32,32,1,1,2,64,true ,0><<<4096,blk,0,stream>>>(W1, tk3, tb3, PG, nullptr,0, 8,64,64,128,128);
  conv_last_k<<<1536,blk,0,stream>>>(PG, tk3c, S, 8,128,128);
  reduce_last_k<<<384,blk,0,stream>>>(S, tb3c, out, 393216);
}

// Round 20
// 451.009 us; speedup vs baseline: 1.0002x; 1.0002x over previous
//
#include <hip/hip_runtime.h>

#define DI __device__ __forceinline__
DI float silu_f(float x){ return x * (1.0f/(1.0f+__expf(-x))); }

template<int X> struct LOG2 { static constexpr int v = 1 + LOG2<X/2>::v; };
template<> struct LOG2<1> { static constexpr int v = 0; };

// ---------------------------------------------------------------------------
// Direct conv (r17/r18 core). G FROZEN (VQ argmin rounding). TOW row-band.
// FG>0: fused input-partial reduce in staging (r19, order == reduce_k).
// r20: DBUF (auto on FG==0 && !SALL && CLEN!=3 && TOW>0, i.e. conv2/conv3):
// double-buffer BOTH sw and si in LDS; stage ky+1 while computing ky; ONE
// barrier per ky. Block-level pipelining via LDS (NOT r9/r13 register
// prefetch — staging stays a 256-stride loop, no VGPR blowup). Writes to
// buf[nxt] never race reads of buf[cur]; end barrier orders both.
// Values + per-output fmaf chain order UNCHANGED everywhere.
// ---------------------------------------------------------------------------
template<int KH,int KW,int STRIDE,int PAD,int CIN,int COUT,int NPIX,
         bool ACT,bool BIAS,int G,int CS,int TOW,int FG>
__global__ __launch_bounds__(256) void conv_k(
    const float* __restrict__ in, const float* __restrict__ w,
    const float* __restrict__ bias, float* __restrict__ out,
    const float* __restrict__ fb, size_t fstr,
    int N,int H,int W,int OH,int OW)
{
  constexpr int CLEN = CIN/G;
  constexpr int COB  = COUT/CS;
  constexpr int COQ  = COB/4;
  constexpr int GSH  = LOG2<G>::v;
  constexpr int CSH  = LOG2<CS>::v;
  constexpr int TAPF = CLEN*COB;
  constexpr bool SALL = (KH*KW*TAPF*4) <= 47*1024;
  constexpr int NTAP = SALL ? KH*KW : KW;
  constexpr bool DBUF = (TOW>0) && !SALL && (CLEN!=3) && (FG==0);
  static_assert(CLEN==3 || (CLEN%4)==0, "ci");
  static_assert(FG==0 || (TOW>0 && CLEN!=3), "fg");
  __shared__ float sw[(DBUF?2:1)*NTAP*TAPF];
  constexpr int SPAN = (TOW>0) ? (TOW-1)*STRIDE + KW : 1;
  constexpr int ROWS = (TOW>0) ? ((256/COQ)*NPIX)/TOW : 1;
  constexpr int CQ4  = (TOW>0 && CLEN!=3) ? CLEN/4 : 1;
  constexpr int SI_F = (TOW==0) ? 1 : (CLEN==3 ? ROWS*SPAN*3 : ROWS*CQ4*SPAN*4);
  __shared__ float si[(DBUF?2:1)*SI_F];
  static_assert(TOW==0 || NPIX<=2, "tow npix");
  static_assert(TOW==0 || ((256/COQ)*NPIX) % TOW == 0, "rows");

  const int g  = blockIdx.x & (G-1);
  const int cs = (blockIdx.x >> GSH) & (CS-1);
  const int bx = blockIdx.x >> (GSH+CSH);
  const int total = N*OH*OW;
  if (G>1) out += (size_t)g * total * COUT;
  const int ci_off  = g*CLEN;
  const int co_base = cs*COB;

  int idx = bx*256 + (int)threadIdx.x;
  int cq = idx % COQ;
  int pg = idx / COQ;
  int co = cq*4;
  int gco = co_base + co;
  int p0 = pg*NPIX;

  float acc[NPIX][4] = {};
  int iy0[NPIX], ix0[NPIX]; const float* base[NPIX]; bool pv[NPIX];
#pragma unroll
  for (int t=0;t<NPIX;t++){
    int p=p0+t; pv[t]=(p<total); int pp=pv[t]?p:0;
    int ox=pp%OW; int r=pp/OW; int oy=r%OH; int n=r/OH;
    iy0[t]=oy*STRIDE-PAD; ix0[t]=ox*STRIDE-PAD;
    base[t]=in+(size_t)n*H*W*CIN + ci_off;
  }

  auto stage = [&](int tap0, float* dst){
    constexpr int TQ = TAPF/4;
    constexpr int V  = NTAP*TQ;
    for (int v=threadIdx.x; v<V; v+=256){
      int tap = v / TQ; int rem = v - tap*TQ;
      float4 q;
      if constexpr (CS==1){
        const float4* src = (const float4*)(w + ((size_t)(tap0+tap)*CIN + ci_off)*COUT);
        q = src[rem];
      } else if constexpr (CLEN==3){
        int ci = rem / (COB/4); int r2 = rem - ci*(COB/4);
        q = *(const float4*)(w + ((size_t)(tap0+tap)*CIN + ci)*COUT
                               + co_base + r2*4);
      } else {
        int ci = rem / (COB/4); int r2 = rem - ci*(COB/4);
        q = *(const float4*)(w + ((size_t)(tap0+tap)*CIN + ci_off + ci)*COUT
                               + co_base + r2*4);
      }
      *(float4*)(dst + (size_t)tap*TAPF + rem*4) = q;
    }
  };

  if constexpr (SALL){
    stage(0, sw);
    __syncthreads();
  }

  if constexpr (TOW>0){
    const int pb0 = bx * ((256/COQ)*NPIX);
    const int r0  = pb0 / TOW;
    const int oy0 = r0 % OH;
    const int n0  = r0 / OH;
    int myrow[NPIX], oxl[NPIX];
#pragma unroll
    for (int t=0;t<NPIX;t++){
      int pl = p0 + t - pb0;
      myrow[t] = pl / TOW;
      oxl[t]   = pl - myrow[t]*TOW;
    }

    auto stage_in = [&](int ky, float* dsi){
      if constexpr (CLEN==3){
        constexpr int INS = ROWS*SPAN;
        for (int v=(int)threadIdx.x; v<INS; v+=256){
          int r  = v / SPAN;
          int ixo= v - r*SPAN;
          int iy = (oy0+r)*STRIDE - PAD + ky;
          int ix = ixo - PAD;
          bool ok = iy>=0 && iy<H && ix>=0 && ix<W;
          const float* ip = in + ((size_t)(n0*H+iy)*W + ix)*CIN;
          dsi[v*3+0] = ok?ip[0]:0.f;
          dsi[v*3+1] = ok?ip[1]:0.f;
          dsi[v*3+2] = ok?ip[2]:0.f;
        }
      } else {
        constexpr int INQ = ROWS*CQ4*SPAN;
        for (int v=(int)threadIdx.x; v<INQ; v+=256){
          int r  = v / (CQ4*SPAN);
          int rm = v - r*(CQ4*SPAN);
          int q  = rm / SPAN;
          int ixo= rm - q*SPAN;
          int iy = (oy0+r)*STRIDE - PAD + ky;
          int ix = ixo - PAD;
          bool ok = iy>=0 && iy<H && ix>=0 && ix<W;
          float4 val = make_float4(0.f,0.f,0.f,0.f);
          if (ok){
            size_t off = ((size_t)(n0*H+iy)*W + ix)*CIN + ci_off + q*4;
            if constexpr (FG>0){
              float a[4]; *(float4*)a = *(const float4*)(in + off);
#pragma unroll
              for (int g2=1; g2<FG; g2++){
                float b[4]; *(float4*)b = *(const float4*)(in + (size_t)g2*fstr + off);
#pragma unroll
                for (int j=0;j<4;j++) a[j]+=b[j];
              }
              float bb[4]; *(float4*)bb = *(const float4*)(fb + ci_off + q*4);
#pragma unroll
              for (int j=0;j<4;j++) a[j] = silu_f(a[j]+bb[j]);
              val = *(float4*)a;
            } else {
              val = *(const float4*)(in + off);
            }
          }
          *(float4*)&dsi[(size_t)v*4] = val;
        }
      }
    };

    auto compute_ky = [&](const float* swr, const float* sib){
      for (int kx=0; kx<KW; kx++){
        const float* swt = swr + (size_t)kx*TAPF;
        if constexpr (CLEN==3){
          float wv[3][4];
          *(float4*)wv[0]=*(const float4*)(swt + 0*COB + co);
          *(float4*)wv[1]=*(const float4*)(swt + 1*COB + co);
          *(float4*)wv[2]=*(const float4*)(swt + 2*COB + co);
#pragma unroll
          for (int t=0;t<NPIX;t++){
            const float* sp = &sib[(size_t)(myrow[t]*SPAN + oxl[t]*STRIDE + kx)*3];
            float v0=sp[0], v1=sp[1], v2=sp[2];
#pragma unroll
            for (int j=0;j<4;j++)
              acc[t][j]=fmaf(v0,wv[0][j],fmaf(v1,wv[1][j],fmaf(v2,wv[2][j],acc[t][j])));
          }
        } else {
#pragma unroll 2
          for (int c=0; c<CQ4; c++){
            float wv[4][4];
#pragma unroll
            for (int r=0;r<4;r++)
              *(float4*)wv[r] = *(const float4*)(swt + (c*4+r)*COB + co);
#pragma unroll
            for (int t=0;t<NPIX;t++){
              float va[4];
              *(float4*)va = *(const float4*)&sib[(size_t)((myrow[t]*CQ4 + c)*SPAN + oxl[t]*STRIDE + kx)*4];
#pragma unroll
              for (int r=0;r<4;r++)
#pragma unroll
                for (int j=0;j<4;j++)
                  acc[t][j]=fmaf(va[r],wv[r][j],acc[t][j]);
            }
          }
        }
      }
    };

    if constexpr (DBUF){
      // software-pipelined: stage ky+1 into buf[nxt] while computing buf[cur]
      stage(0, sw);
      stage_in(0, si);
      __syncthreads();
      for (int ky=0; ky<KH; ky++){
        const int cur = ky&1, nxt = cur^1;
        if (ky+1<KH){
          stage((ky+1)*KW, sw + (size_t)nxt*NTAP*TAPF);
          stage_in(ky+1, si + (size_t)nxt*SI_F);
        }
        compute_ky(sw + (size_t)cur*NTAP*TAPF, si + (size_t)cur*SI_F);
        __syncthreads();
      }
    } else {
      for (int ky=0; ky<KH; ky++){
        __syncthreads();
        if constexpr (!SALL) stage(ky*KW, sw);
        stage_in(ky, si);
        __syncthreads();
        const float* swr = SALL ? sw + (size_t)ky*KW*TAPF : sw;
        compute_ky(swr, si);
      }
    }
  } else {
    for (int ky=0; ky<KH; ky++){
      if constexpr (!SALL){
        __syncthreads();
        stage(ky*KW, sw);
        __syncthreads();
      }
      const float* swr = SALL ? sw + (size_t)ky*KW*TAPF : sw;
      for (int kx=0; kx<KW; kx++){
        const float* swt = swr + (size_t)kx*TAPF;
        const float* ip[NPIX]; bool ok[NPIX];
#pragma unroll
        for (int t=0;t<NPIX;t++){
          int iy=iy0[t]+ky, ix=ix0[t]+kx;
          ok[t]=pv[t] && iy>=0 && iy<H && ix>=0 && ix<W;
          ip[t]=base[t]+(size_t)(iy*W+ix)*CIN;
        }
        if constexpr (CLEN==3){
          float wv[3][4];
          *(float4*)wv[0]=*(const float4*)(swt + 0*COB + co);
          *(float4*)wv[1]=*(const float4*)(swt + 1*COB + co);
          *(float4*)wv[2]=*(const float4*)(swt + 2*COB + co);
#pragma unroll
          for (int t=0;t<NPIX;t++){
            float v0=ok[t]?ip[t][0]:0.f;
            float v1=ok[t]?ip[t][1]:0.f;
            float v2=ok[t]?ip[t][2]:0.f;
#pragma unroll
            for (int j=0;j<4;j++)
              acc[t][j]=fmaf(v0,wv[0][j],fmaf(v1,wv[1][j],fmaf(v2,wv[2][j],acc[t][j])));
          }
        } else {
#pragma unroll 2
          for (int ci=0; ci<CLEN; ci+=4){
            float wv[4][4];
#pragma unroll
            for (int r=0;r<4;r++)
              *(float4*)wv[r] = *(const float4*)(swt + (ci+r)*COB + co);
#pragma unroll
            for (int t=0;t<NPIX;t++){
              float va[4];
              *(float4*)va = ok[t] ? *(const float4*)(ip[t]+ci)
                                   : make_float4(0.f,0.f,0.f,0.f);
#pragma unroll
              for (int r=0;r<4;r++)
#pragma unroll
                for (int j=0;j<4;j++)
                  acc[t][j]=fmaf(va[r],wv[r][j],acc[t][j]);
            }
          }
        }
      }
    }
  }

  float bv[4]={0.f,0.f,0.f,0.f};
  if constexpr (BIAS) *(float4*)bv = *(const float4*)(bias+gco);
#pragma unroll
  for (int t=0;t<NPIX;t++) if (pv[t]){
    float o[4];
#pragma unroll
    for (int j=0;j<4;j++){
      float v = acc[t][j]+bv[j];
      o[j] = ACT ? silu_f(v) : v;
    }
    *(float4*)(out + (size_t)(p0+t)*COUT + gco) = *(float4*)o;
  }
}

// ---------------------------------------------------------------------------
// conv_transpose 5x5 s2 SAME, single-stage row-band (r18) + FG fused reduce.
// ---------------------------------------------------------------------------
template<int CIN,int COUT,int NPIX,int G,int CS,int IW,bool DIRECT,int FG>
__global__ __launch_bounds__(256) void tconv_rb(
    const float* __restrict__ in, const float* __restrict__ w,
    const float* __restrict__ bias, float* __restrict__ out,
    const float* __restrict__ fb, size_t fstr,
    int N,int H,int W,int OH,int OW)
{
  constexpr int CLEN = CIN/G;
  constexpr int COB  = COUT/CS;
  constexpr int COQ  = COB/4;
  constexpr int GSH  = LOG2<G>::v;
  constexpr int CSH  = LOG2<CS>::v;
  constexpr int TAPF = CLEN*COB;
  constexpr int PPB  = (256/COQ)*NPIX;
  static_assert(PPB % IW == 0, "whole rows");
  constexpr int ROWS_O = PPB/IW;
  constexpr int NRI  = ROWS_O + 2;
  constexpr int SPAN = IW + 2;
  constexpr int CQ4  = CLEN/4;
  __shared__ float sw[9*TAPF];
  __shared__ float si[NRI*CQ4*SPAN*4];

  const int par = blockIdx.x & 3;
  const int py = par>>1, px = par&1;
  const int g  = (blockIdx.x>>2) & (G-1);
  const int cs = (blockIdx.x>>(2+GSH)) & (CS-1);
  const int bx = blockIdx.x >> (2+GSH+CSH);
  const int NKY = py?3:2, NKX = px?3:2;
  const int OHh = OH>>1;
  if (G>1) out += (size_t)g * (size_t)N*OH*OW*COUT;
  const int co_base = cs*COB;

  const int tid = (int)threadIdx.x;
  int idx = bx*256 + tid;
  int cq = idx % COQ;
  int pg = idx / COQ;
  int co = cq*4;
  int p0 = pg*NPIX;
  const int pb0 = bx*PPB;
  const int R0  = pb0 / IW;
  const int oy0 = R0 % OHh;
  const int n0  = R0 / OHh;

  int myrow[NPIX], xx[NPIX];
#pragma unroll
  for (int t=0;t<NPIX;t++){
    int lp = p0 + t - pb0;
    myrow[t] = lp / IW;
    xx[t]    = lp - myrow[t]*IW;
  }

  {
    constexpr int TQ = TAPF/4;
    const int V = NKY*NKX*TQ;
    for (int v=tid; v<V; v+=256){
      int tap = v / TQ; int rem = v - tap*TQ;
      int j = tap / NKX, i = tap - j*NKX;
      int ky = 2*j + (py?0:1), kx = 2*i + (px?0:1);
      int ci = rem / (COB/4); int r2 = rem - ci*(COB/4);
      float4 q = *(const float4*)(w + ((size_t)(ky*5+kx)*CIN + g*CLEN + ci)*COUT
                                    + co_base + r2*4);
      *(float4*)(sw + (size_t)(j*3+i)*TAPF + rem*4) = q;
    }
  }
  {
    constexpr int INQ = NRI*CQ4*SPAN;
    for (int v=tid; v<INQ; v+=256){
      int r  = v / (CQ4*SPAN);
      int rm = v - r*(CQ4*SPAN);
      int q  = rm / SPAN;
      int cc = rm - q*SPAN;
      int iy = oy0 - 1 + r;
      int ix = cc - 1;
      bool ok = iy>=0 && iy<H && ix>=0 && ix<W;
      float4 val = make_float4(0.f,0.f,0.f,0.f);
      if (ok){
        size_t off = ((size_t)(n0*H+iy)*W + ix)*CIN + g*CLEN + q*4;
        if constexpr (FG>0){
          float a[4]; *(float4*)a = *(const float4*)(in + off);
#pragma unroll
          for (int g2=1; g2<FG; g2++){
            float b[4]; *(float4*)b = *(const float4*)(in + (size_t)g2*fstr + off);
#pragma unroll
            for (int j=0;j<4;j++) a[j]+=b[j];
          }
          float bb[4]; *(float4*)bb = *(const float4*)(fb + g*CLEN + q*4);
#pragma unroll
          for (int j=0;j<4;j++) a[j] = silu_f(a[j]+bb[j]);
          val = *(float4*)a;
        } else {
          val = *(const float4*)(in + off);
        }
      }
      *(float4*)&si[(size_t)v*4] = val;
    }
  }
  __syncthreads();

  float acc[NPIX][4] = {};
  for (int j=0;j<NKY;j++){
    for (int i=0;i<NKX;i++){
      const float* swt = sw + (size_t)(j*3+i)*TAPF;
#pragma unroll 2
      for (int c=0;c<CQ4;c++){
        float wv[4][4];
#pragma unroll
        for (int r=0;r<4;r++)
          *(float4*)wv[r] = *(const float4*)(swt + (c*4+r)*COB + co);
#pragma unroll
        for (int t=0;t<NPIX;t++){
          float va[4];
          *(float4*)va = *(const float4*)&si[(size_t)(((myrow[t]+j)*CQ4 + c)*SPAN + (xx[t]+i))*4];
#pragma unroll
          for (int r=0;r<4;r++)
#pragma unroll
            for (int jj=0;jj<4;jj++)
              acc[t][jj]=fmaf(va[r],wv[r][jj],acc[t][jj]);
        }
      }
    }
  }

  float bv[4]={0.f,0.f,0.f,0.f};
  if constexpr (DIRECT) *(float4*)bv = *(const float4*)(bias+co_base+co);
#pragma unroll
  for (int t=0;t<NPIX;t++){
    float o[4];
#pragma unroll
    for (int jj=0;jj<4;jj++){
      float v = acc[t][jj]+bv[jj];
      o[jj] = DIRECT ? silu_f(v) : v;
    }
    *(float4*)(out + (((size_t)n0*OH + (2*(oy0+myrow[t])+py))*OW + (2*xx[t]+px))*COUT + co_base+co) = *(float4*)o;
  }
}

// ---------------------------------------------------------------------------
// VQ fused with conv3c 2-partial reduction + bias (round-2 EXACT — FROZEN).
// ---------------------------------------------------------------------------
__global__ __launch_bounds__(256) void vq_k(
    const float* __restrict__ p, const float* __restrict__ bias,
    const float* __restrict__ cb, float* __restrict__ q, int NLat)
{
  __shared__ float slat[4][128];
  int wave = threadIdx.x >> 6;
  int lane = threadIdx.x & 63;
  int l = blockIdx.x*4 + wave;
  if (l >= NLat) return;
  const float* p0 = p + (size_t)l*128;
  const float* p1 = p0 + (size_t)NLat*128;
  slat[wave][lane]    = p0[lane]    + p1[lane]    + bias[lane];
  slat[wave][lane+64] = p0[lane+64] + p1[lane+64] + bias[lane+64];

  float bestd = INFINITY; int besti = 0;
  for (int c0=0;c0<256;c0+=64){
    int c = c0 + lane;
    const float* cp = cb + (size_t)c*128;
    float d = 0.f;
#pragma unroll 8
    for (int k=0;k<128;k+=4){
      float4 cv = *reinterpret_cast<const float4*>(cp+k);
      float d0 = slat[wave][k+0]-cv.x;
      float d1 = slat[wave][k+1]-cv.y;
      float d2 = slat[wave][k+2]-cv.z;
      float d3 = slat[wave][k+3]-cv.w;
      d += d0*d0; d += d1*d1; d += d2*d2; d += d3*d3;
    }
    if (d < bestd) { bestd = d; besti = c; }
  }
  for (int off=32; off; off>>=1){
    float od = __shfl_down(bestd, off);
    int   oi = __shfl_down(besti, off);
    if (od < bestd || (od == bestd && oi < besti)) { bestd=od; besti=oi; }
  }
  besti = __shfl(besti, 0);
  const float* cp = cb + (size_t)besti*128;
  float* qp = q + (size_t)l*128;
  qp[lane]    = cp[lane];
  qp[lane+64] = cp[lane+64];
}

// ---------------------------------------------------------------------------
// Final 3x3 conv 32->3 split over ky rows (g = blockIdx%3). Writes partials.
// ---------------------------------------------------------------------------
__global__ __launch_bounds__(256) void conv_last_k(
    const float* __restrict__ in, const float* __restrict__ w,
    float* __restrict__ p, int N,int H,int W)
{
  int g = blockIdx.x % 3;
  int bx = blockIdx.x / 3;
  int pix = bx*256 + threadIdx.x;
  int total = N*H*W;
  if (pix>=total) return;
  int x = pix % W; int r = pix / W; int y = r % H; int n = r / H;
  float a0=0.f, a1=0.f, a2=0.f;
  int iy = y + g - 1;
  if (iy>=0 && iy<H){
    const float* base = in + ((size_t)n*H + iy)*W*32;
    for (int kx=0;kx<3;kx++){
      int ix=x+kx-1; if(ix<0||ix>=W) continue;
      const float* ip = base + (size_t)ix*32;
      const float* wp = w + (size_t)((g*3+kx)*32)*3;
#pragma unroll
      for (int ci=0;ci<32;ci+=4){
        float va[4]; *(float4*)va = *(const float4*)(ip+ci);
        float wv[12];
        *(float4*)(wv+0) = *(const float4*)(wp+ci*3+0);
        *(float4*)(wv+4) = *(const float4*)(wp+ci*3+4);
        *(float4*)(wv+8) = *(const float4*)(wp+ci*3+8);
#pragma unroll
        for (int r2=0;r2<4;r2++){
          a0 = fmaf(va[r2], wv[r2*3+0], a0);
          a1 = fmaf(va[r2], wv[r2*3+1], a1);
          a2 = fmaf(va[r2], wv[r2*3+2], a2);
        }
      }
    }
  }
  float* pp = p + (size_t)g*total*3 + (size_t)pix*3;
  pp[0]=a0; pp[1]=a1; pp[2]=a2;
}

__global__ __launch_bounds__(256) void reduce_last_k(
    const float* __restrict__ p, const float* __restrict__ bias,
    float* __restrict__ out, int n)
{
  int i = (blockIdx.x*256+threadIdx.x)*4;
  if (i>=n) return;
  float a[4]; *(float4*)a = *(const float4*)(p+i);
#pragma unroll
  for (int g=1; g<3; g++){
    float b[4]; *(float4*)b = *(const float4*)(p+(size_t)g*n+i);
#pragma unroll
    for (int j=0;j<4;j++) a[j]+=b[j];
  }
  float o[4];
#pragma unroll
  for (int j=0;j<4;j++) o[j] = a[j] + bias[(i+j)%3];
  *(float4*)(out+i) = *(float4*)o;
}

extern "C" void kernel_launch(void* const* d_in, const int* in_sizes, int n_in,
                              void* d_out, int out_size, void* d_ws, size_t ws_size,
                              hipStream_t stream) {
  const float* x    = (const float*)d_in[0];
  const float* k1   = (const float*)d_in[1];  const float* b1  = (const float*)d_in[2];
  const float* k1c  = (const float*)d_in[3];  const float* b1c = (const float*)d_in[4];
  const float* k2   = (const float*)d_in[5];  const float* b2  = (const float*)d_in[6];
  const float* k2c  = (const float*)d_in[7];  const float* b2c = (const float*)d_in[8];
  const float* k3   = (const float*)d_in[9];  const float* b3  = (const float*)d_in[10];
  const float* k3c  = (const float*)d_in[11]; const float* b3c = (const float*)d_in[12];
  const float* cb   = (const float*)d_in[13];
  const float* tk1  = (const float*)d_in[14]; const float* tb1  = (const float*)d_in[15];
  const float* tk1c = (const float*)d_in[16]; const float* tb1c = (const float*)d_in[17];
  const float* tk2  = (const float*)d_in[18]; const float* tb2  = (const float*)d_in[19];
  const float* tk2c = (const float*)d_in[20]; const float* tb2c = (const float*)d_in[21];
  const float* tk3  = (const float*)d_in[22]; const float* tb3  = (const float*)d_in[23];
  const float* tk3c = (const float*)d_in[24]; const float* tb3c = (const float*)d_in[25];
  float* out = (float*)d_out;

  float* S  = (float*)d_ws;
  float* W0 = S;                 // [0 .. 1M) floats
  float* W1 = S + 1048576;       // [1M .. 2M)
  float* PA = S + 2097152;       // conv2 partials   [2M..3M)
  float* PB = S + 3145728;       // conv3 partials   [3M..4M)
  float* PC = S + 2097152;       // conv3c partials  [2M..2.5M)
  float* PD = S + 2097152;       // tconv1 partials  [2M..4M)
  float* PE = S + 4194304;       // tk1c partials    [4M..5M)
  float* PF = S + 2097152;       // tconv2 partials  [2M..4M)
  float* PG = S + 2097152;       // tconv3 output    [2M..6M)
  dim3 blk(256);

  // ---- encoder: G-splits + fmaf/reduce order FROZEN (VQ argmin) ----
  conv_k<11,11,2,4,  3, 32,2,true ,true ,1,2,64,0><<< 512,blk,0,stream>>>(x,  k1,  b1,  W0, nullptr,0, 8,128,128,64,64);
  conv_k< 3, 3,1,1, 32, 32,2,true ,true ,1,2,64,0><<< 512,blk,0,stream>>>(W0, k1c, b1c, W1, nullptr,0, 8,64,64,64,64);
  // conv2: DBUF pipelined (62.3KB LDS, 2 blocks/CU)
  conv_k<11,11,2,4, 32, 64,2,false,false,2,2,32,0><<< 512,blk,0,stream>>>(W1, k2,  nullptr, PA, nullptr,0, 8,64,64,32,32);
  conv_k< 3, 3,1,1, 64, 64,1,true ,true ,1,2,32,2><<< 512,blk,0,stream>>>(PA, k2c, b2c, W0, b2,524288, 8,32,32,32,32);
  // conv3: DBUF pipelined (64.5KB LDS, 2 blocks/CU)
  conv_k<11,11,2,4, 64,128,2,false,false,4,4,16,0><<< 512,blk,0,stream>>>(W0, k3,  nullptr, PB, nullptr,0, 8,32,32,16,16);
  conv_k< 3, 3,1,1,128,128,1,false,false,2,4,16,4><<< 512,blk,0,stream>>>(PB, k3c, nullptr, PC, b3,262144, 8,16,16,16,16);
  // ---- VQ (FROZEN; reads conv3c partials) ----
  vq_k<<<512,blk,0,stream>>>(PC, b3c, cb, W1, 2048);
  // ---- decoder ----
  tconv_rb<128,64,1,4,2,16,false,0><<<2048,blk,0,stream>>>(W1, tk1, nullptr, PD, nullptr,0, 8,16,16,32,32);
  conv_k< 3, 3,1,1, 64, 64,2,false,false,2,4,32,4><<< 512,blk,0,stream>>>(PD, tk1c, nullptr, PE, tb1,524288, 8,32,32,32,32);
  tconv_rb< 64,32,1,2,1,32,false,2><<<2048,blk,0,stream>>>(PE, tk2, nullptr, PF, tb1c,524288, 8,32,32,64,64);
  conv_k< 3, 3,1,1, 32, 32,2,true ,true ,1,2,64,2><<< 512,blk,0,stream>>>(PF, tk2c, tb2c, W1, tb2,1048576, 8,64,64,64,64);
  tconv_rb< 32,32,1,1,2,64,true ,0><<<4096,blk,0,stream>>>(W1, tk3, tb3, PG, nullptr,0, 8,64,64,128,128);
  conv_last_k<<<1536,blk,0,stream>>>(PG, tk3c, S, 8,128,128);
  reduce_last_k<<<384,blk,0,stream>>>(S, tb3c, out, 393216);
}

// Round 21
// 446.963 us; speedup vs baseline: 1.0092x; 1.0091x over previous
//
#include <hip/hip_runtime.h>

#define DI __device__ __forceinline__
DI float silu_f(float x){ return x * (1.0f/(1.0f+__expf(-x))); }

template<int X> struct LOG2 { static constexpr int v = 1 + LOG2<X/2>::v; };
template<> struct LOG2<1> { static constexpr int v = 0; };

// ---------------------------------------------------------------------------
// Direct conv (r20 core). G FROZEN (VQ argmin rounding). TOW row-band LDS.
// FG>0: fused input-partial reduce in staging (order == reduce_k).
// DBUF on conv2/conv3 (neutral but free). r21: CLEN==3 si entries padded to
// 4 floats -> one ds_read_b128 per tap instead of 3x b32 (values identical).
// Per-output fmaf chain order UNCHANGED everywhere.
// ---------------------------------------------------------------------------
template<int KH,int KW,int STRIDE,int PAD,int CIN,int COUT,int NPIX,
         bool ACT,bool BIAS,int G,int CS,int TOW,int FG>
__global__ __launch_bounds__(256) void conv_k(
    const float* __restrict__ in, const float* __restrict__ w,
    const float* __restrict__ bias, float* __restrict__ out,
    const float* __restrict__ fb, size_t fstr,
    int N,int H,int W,int OH,int OW)
{
  constexpr int CLEN = CIN/G;
  constexpr int COB  = COUT/CS;
  constexpr int COQ  = COB/4;
  constexpr int GSH  = LOG2<G>::v;
  constexpr int CSH  = LOG2<CS>::v;
  constexpr int TAPF = CLEN*COB;
  constexpr bool SALL = (KH*KW*TAPF*4) <= 47*1024;
  constexpr int NTAP = SALL ? KH*KW : KW;
  constexpr bool DBUF = (TOW>0) && !SALL && (CLEN!=3) && (FG==0);
  static_assert(CLEN==3 || (CLEN%4)==0, "ci");
  static_assert(FG==0 || (TOW>0 && CLEN!=3), "fg");
  __shared__ float sw[(DBUF?2:1)*NTAP*TAPF];
  constexpr int SPAN = (TOW>0) ? (TOW-1)*STRIDE + KW : 1;
  constexpr int ROWS = (TOW>0) ? ((256/COQ)*NPIX)/TOW : 1;
  constexpr int CQ4  = (TOW>0 && CLEN!=3) ? CLEN/4 : 1;
  constexpr int SI_F = (TOW==0) ? 1 : (CLEN==3 ? ROWS*SPAN*4 : ROWS*CQ4*SPAN*4);
  __shared__ float si[(DBUF?2:1)*SI_F];
  static_assert(TOW==0 || NPIX<=2, "tow npix");
  static_assert(TOW==0 || ((256/COQ)*NPIX) % TOW == 0, "rows");

  const int g  = blockIdx.x & (G-1);
  const int cs = (blockIdx.x >> GSH) & (CS-1);
  const int bx = blockIdx.x >> (GSH+CSH);
  const int total = N*OH*OW;
  if (G>1) out += (size_t)g * total * COUT;
  const int ci_off  = g*CLEN;
  const int co_base = cs*COB;

  int idx = bx*256 + (int)threadIdx.x;
  int cq = idx % COQ;
  int pg = idx / COQ;
  int co = cq*4;
  int gco = co_base + co;
  int p0 = pg*NPIX;

  float acc[NPIX][4] = {};
  int iy0[NPIX], ix0[NPIX]; const float* base[NPIX]; bool pv[NPIX];
#pragma unroll
  for (int t=0;t<NPIX;t++){
    int p=p0+t; pv[t]=(p<total); int pp=pv[t]?p:0;
    int ox=pp%OW; int r=pp/OW; int oy=r%OH; int n=r/OH;
    iy0[t]=oy*STRIDE-PAD; ix0[t]=ox*STRIDE-PAD;
    base[t]=in+(size_t)n*H*W*CIN + ci_off;
  }

  auto stage = [&](int tap0, float* dst){
    constexpr int TQ = TAPF/4;
    constexpr int V  = NTAP*TQ;
    for (int v=threadIdx.x; v<V; v+=256){
      int tap = v / TQ; int rem = v - tap*TQ;
      float4 q;
      if constexpr (CS==1){
        const float4* src = (const float4*)(w + ((size_t)(tap0+tap)*CIN + ci_off)*COUT);
        q = src[rem];
      } else if constexpr (CLEN==3){
        int ci = rem / (COB/4); int r2 = rem - ci*(COB/4);
        q = *(const float4*)(w + ((size_t)(tap0+tap)*CIN + ci)*COUT
                               + co_base + r2*4);
      } else {
        int ci = rem / (COB/4); int r2 = rem - ci*(COB/4);
        q = *(const float4*)(w + ((size_t)(tap0+tap)*CIN + ci_off + ci)*COUT
                               + co_base + r2*4);
      }
      *(float4*)(dst + (size_t)tap*TAPF + rem*4) = q;
    }
  };

  if constexpr (SALL){
    stage(0, sw);
    __syncthreads();
  }

  if constexpr (TOW>0){
    const int pb0 = bx * ((256/COQ)*NPIX);
    const int r0  = pb0 / TOW;
    const int oy0 = r0 % OH;
    const int n0  = r0 / OH;
    int myrow[NPIX], oxl[NPIX];
#pragma unroll
    for (int t=0;t<NPIX;t++){
      int pl = p0 + t - pb0;
      myrow[t] = pl / TOW;
      oxl[t]   = pl - myrow[t]*TOW;
    }

    auto stage_in = [&](int ky, float* dsi){
      if constexpr (CLEN==3){
        constexpr int INS = ROWS*SPAN;
        for (int v=(int)threadIdx.x; v<INS; v+=256){
          int r  = v / SPAN;
          int ixo= v - r*SPAN;
          int iy = (oy0+r)*STRIDE - PAD + ky;
          int ix = ixo - PAD;
          bool ok = iy>=0 && iy<H && ix>=0 && ix<W;
          const float* ip = in + ((size_t)(n0*H+iy)*W + ix)*CIN;
          float v0 = ok?ip[0]:0.f, v1 = ok?ip[1]:0.f, v2 = ok?ip[2]:0.f;
          *(float4*)&dsi[(size_t)v*4] = make_float4(v0,v1,v2,0.f);
        }
      } else {
        constexpr int INQ = ROWS*CQ4*SPAN;
        for (int v=(int)threadIdx.x; v<INQ; v+=256){
          int r  = v / (CQ4*SPAN);
          int rm = v - r*(CQ4*SPAN);
          int q  = rm / SPAN;
          int ixo= rm - q*SPAN;
          int iy = (oy0+r)*STRIDE - PAD + ky;
          int ix = ixo - PAD;
          bool ok = iy>=0 && iy<H && ix>=0 && ix<W;
          float4 val = make_float4(0.f,0.f,0.f,0.f);
          if (ok){
            size_t off = ((size_t)(n0*H+iy)*W + ix)*CIN + ci_off + q*4;
            if constexpr (FG>0){
              float a[4]; *(float4*)a = *(const float4*)(in + off);
#pragma unroll
              for (int g2=1; g2<FG; g2++){
                float b[4]; *(float4*)b = *(const float4*)(in + (size_t)g2*fstr + off);
#pragma unroll
                for (int j=0;j<4;j++) a[j]+=b[j];
              }
              float bb[4]; *(float4*)bb = *(const float4*)(fb + ci_off + q*4);
#pragma unroll
              for (int j=0;j<4;j++) a[j] = silu_f(a[j]+bb[j]);
              val = *(float4*)a;
            } else {
              val = *(const float4*)(in + off);
            }
          }
          *(float4*)&dsi[(size_t)v*4] = val;
        }
      }
    };

    auto compute_ky = [&](const float* swr, const float* sib){
      for (int kx=0; kx<KW; kx++){
        const float* swt = swr + (size_t)kx*TAPF;
        if constexpr (CLEN==3){
          float wv[3][4];
          *(float4*)wv[0]=*(const float4*)(swt + 0*COB + co);
          *(float4*)wv[1]=*(const float4*)(swt + 1*COB + co);
          *(float4*)wv[2]=*(const float4*)(swt + 2*COB + co);
#pragma unroll
          for (int t=0;t<NPIX;t++){
            float vq4[4];
            *(float4*)vq4 = *(const float4*)&sib[(size_t)(myrow[t]*SPAN + oxl[t]*STRIDE + kx)*4];
#pragma unroll
            for (int j=0;j<4;j++)
              acc[t][j]=fmaf(vq4[0],wv[0][j],fmaf(vq4[1],wv[1][j],fmaf(vq4[2],wv[2][j],acc[t][j])));
          }
        } else {
#pragma unroll 2
          for (int c=0; c<CQ4; c++){
            float wv[4][4];
#pragma unroll
            for (int r=0;r<4;r++)
              *(float4*)wv[r] = *(const float4*)(swt + (c*4+r)*COB + co);
#pragma unroll
            for (int t=0;t<NPIX;t++){
              float va[4];
              *(float4*)va = *(const float4*)&sib[(size_t)((myrow[t]*CQ4 + c)*SPAN + oxl[t]*STRIDE + kx)*4];
#pragma unroll
              for (int r=0;r<4;r++)
#pragma unroll
                for (int j=0;j<4;j++)
                  acc[t][j]=fmaf(va[r],wv[r][j],acc[t][j]);
            }
          }
        }
      }
    };

    if constexpr (DBUF){
      stage(0, sw);
      stage_in(0, si);
      __syncthreads();
      for (int ky=0; ky<KH; ky++){
        const int cur = ky&1, nxt = cur^1;
        if (ky+1<KH){
          stage((ky+1)*KW, sw + (size_t)nxt*NTAP*TAPF);
          stage_in(ky+1, si + (size_t)nxt*SI_F);
        }
        compute_ky(sw + (size_t)cur*NTAP*TAPF, si + (size_t)cur*SI_F);
        __syncthreads();
      }
    } else {
      for (int ky=0; ky<KH; ky++){
        __syncthreads();
        if constexpr (!SALL) stage(ky*KW, sw);
        stage_in(ky, si);
        __syncthreads();
        const float* swr = SALL ? sw + (size_t)ky*KW*TAPF : sw;
        compute_ky(swr, si);
      }
    }
  } else {
    for (int ky=0; ky<KH; ky++){
      if constexpr (!SALL){
        __syncthreads();
        stage(ky*KW, sw);
        __syncthreads();
      }
      const float* swr = SALL ? sw + (size_t)ky*KW*TAPF : sw;
      for (int kx=0; kx<KW; kx++){
        const float* swt = swr + (size_t)kx*TAPF;
        const float* ip[NPIX]; bool ok[NPIX];
#pragma unroll
        for (int t=0;t<NPIX;t++){
          int iy=iy0[t]+ky, ix=ix0[t]+kx;
          ok[t]=pv[t] && iy>=0 && iy<H && ix>=0 && ix<W;
          ip[t]=base[t]+(size_t)(iy*W+ix)*CIN;
        }
        if constexpr (CLEN==3){
          float wv[3][4];
          *(float4*)wv[0]=*(const float4*)(swt + 0*COB + co);
          *(float4*)wv[1]=*(const float4*)(swt + 1*COB + co);
          *(float4*)wv[2]=*(const float4*)(swt + 2*COB + co);
#pragma unroll
          for (int t=0;t<NPIX;t++){
            float v0=ok[t]?ip[t][0]:0.f;
            float v1=ok[t]?ip[t][1]:0.f;
            float v2=ok[t]?ip[t][2]:0.f;
#pragma unroll
            for (int j=0;j<4;j++)
              acc[t][j]=fmaf(v0,wv[0][j],fmaf(v1,wv[1][j],fmaf(v2,wv[2][j],acc[t][j])));
          }
        } else {
#pragma unroll 2
          for (int ci=0; ci<CLEN; ci+=4){
            float wv[4][4];
#pragma unroll
            for (int r=0;r<4;r++)
              *(float4*)wv[r] = *(const float4*)(swt + (ci+r)*COB + co);
#pragma unroll
            for (int t=0;t<NPIX;t++){
              float va[4];
              *(float4*)va = ok[t] ? *(const float4*)(ip[t]+ci)
                                   : make_float4(0.f,0.f,0.f,0.f);
#pragma unroll
              for (int r=0;r<4;r++)
#pragma unroll
                for (int j=0;j<4;j++)
                  acc[t][j]=fmaf(va[r],wv[r][j],acc[t][j]);
            }
          }
        }
      }
    }
  }

  float bv[4]={0.f,0.f,0.f,0.f};
  if constexpr (BIAS) *(float4*)bv = *(const float4*)(bias+gco);
#pragma unroll
  for (int t=0;t<NPIX;t++) if (pv[t]){
    float o[4];
#pragma unroll
    for (int j=0;j<4;j++){
      float v = acc[t][j]+bv[j];
      o[j] = ACT ? silu_f(v) : v;
    }
    *(float4*)(out + (size_t)(p0+t)*COUT + gco) = *(float4*)o;
  }
}

// ---------------------------------------------------------------------------
// conv_transpose 5x5 s2 SAME, single-stage row-band (r18) + FG fused reduce.
// ---------------------------------------------------------------------------
template<int CIN,int COUT,int NPIX,int G,int CS,int IW,bool DIRECT,int FG>
__global__ __launch_bounds__(256) void tconv_rb(
    const float* __restrict__ in, const float* __restrict__ w,
    const float* __restrict__ bias, float* __restrict__ out,
    const float* __restrict__ fb, size_t fstr,
    int N,int H,int W,int OH,int OW)
{
  constexpr int CLEN = CIN/G;
  constexpr int COB  = COUT/CS;
  constexpr int COQ  = COB/4;
  constexpr int GSH  = LOG2<G>::v;
  constexpr int CSH  = LOG2<CS>::v;
  constexpr int TAPF = CLEN*COB;
  constexpr int PPB  = (256/COQ)*NPIX;
  static_assert(PPB % IW == 0, "whole rows");
  constexpr int ROWS_O = PPB/IW;
  constexpr int NRI  = ROWS_O + 2;
  constexpr int SPAN = IW + 2;
  constexpr int CQ4  = CLEN/4;
  __shared__ float sw[9*TAPF];
  __shared__ float si[NRI*CQ4*SPAN*4];

  const int par = blockIdx.x & 3;
  const int py = par>>1, px = par&1;
  const int g  = (blockIdx.x>>2) & (G-1);
  const int cs = (blockIdx.x>>(2+GSH)) & (CS-1);
  const int bx = blockIdx.x >> (2+GSH+CSH);
  const int NKY = py?3:2, NKX = px?3:2;
  const int OHh = OH>>1;
  if (G>1) out += (size_t)g * (size_t)N*OH*OW*COUT;
  const int co_base = cs*COB;

  const int tid = (int)threadIdx.x;
  int idx = bx*256 + tid;
  int cq = idx % COQ;
  int pg = idx / COQ;
  int co = cq*4;
  int p0 = pg*NPIX;
  const int pb0 = bx*PPB;
  const int R0  = pb0 / IW;
  const int oy0 = R0 % OHh;
  const int n0  = R0 / OHh;

  int myrow[NPIX], xx[NPIX];
#pragma unroll
  for (int t=0;t<NPIX;t++){
    int lp = p0 + t - pb0;
    myrow[t] = lp / IW;
    xx[t]    = lp - myrow[t]*IW;
  }

  {
    constexpr int TQ = TAPF/4;
    const int V = NKY*NKX*TQ;
    for (int v=tid; v<V; v+=256){
      int tap = v / TQ; int rem = v - tap*TQ;
      int j = tap / NKX, i = tap - j*NKX;
      int ky = 2*j + (py?0:1), kx = 2*i + (px?0:1);
      int ci = rem / (COB/4); int r2 = rem - ci*(COB/4);
      float4 q = *(const float4*)(w + ((size_t)(ky*5+kx)*CIN + g*CLEN + ci)*COUT
                                    + co_base + r2*4);
      *(float4*)(sw + (size_t)(j*3+i)*TAPF + rem*4) = q;
    }
  }
  {
    constexpr int INQ = NRI*CQ4*SPAN;
    for (int v=tid; v<INQ; v+=256){
      int r  = v / (CQ4*SPAN);
      int rm = v - r*(CQ4*SPAN);
      int q  = rm / SPAN;
      int cc = rm - q*SPAN;
      int iy = oy0 - 1 + r;
      int ix = cc - 1;
      bool ok = iy>=0 && iy<H && ix>=0 && ix<W;
      float4 val = make_float4(0.f,0.f,0.f,0.f);
      if (ok){
        size_t off = ((size_t)(n0*H+iy)*W + ix)*CIN + g*CLEN + q*4;
        if constexpr (FG>0){
          float a[4]; *(float4*)a = *(const float4*)(in + off);
#pragma unroll
          for (int g2=1; g2<FG; g2++){
            float b[4]; *(float4*)b = *(const float4*)(in + (size_t)g2*fstr + off);
#pragma unroll
            for (int j=0;j<4;j++) a[j]+=b[j];
          }
          float bb[4]; *(float4*)bb = *(const float4*)(fb + g*CLEN + q*4);
#pragma unroll
          for (int j=0;j<4;j++) a[j] = silu_f(a[j]+bb[j]);
          val = *(float4*)a;
        } else {
          val = *(const float4*)(in + off);
        }
      }
      *(float4*)&si[(size_t)v*4] = val;
    }
  }
  __syncthreads();

  float acc[NPIX][4] = {};
  for (int j=0;j<NKY;j++){
    for (int i=0;i<NKX;i++){
      const float* swt = sw + (size_t)(j*3+i)*TAPF;
#pragma unroll 2
      for (int c=0;c<CQ4;c++){
        float wv[4][4];
#pragma unroll
        for (int r=0;r<4;r++)
          *(float4*)wv[r] = *(const float4*)(swt + (c*4+r)*COB + co);
#pragma unroll
        for (int t=0;t<NPIX;t++){
          float va[4];
          *(float4*)va = *(const float4*)&si[(size_t)(((myrow[t]+j)*CQ4 + c)*SPAN + (xx[t]+i))*4];
#pragma unroll
          for (int r=0;r<4;r++)
#pragma unroll
            for (int jj=0;jj<4;jj++)
              acc[t][jj]=fmaf(va[r],wv[r][jj],acc[t][jj]);
        }
      }
    }
  }

  float bv[4]={0.f,0.f,0.f,0.f};
  if constexpr (DIRECT) *(float4*)bv = *(const float4*)(bias+co_base+co);
#pragma unroll
  for (int t=0;t<NPIX;t++){
    float o[4];
#pragma unroll
    for (int jj=0;jj<4;jj++){
      float v = acc[t][jj]+bv[jj];
      o[jj] = DIRECT ? silu_f(v) : v;
    }
    *(float4*)(out + (((size_t)n0*OH + (2*(oy0+myrow[t])+py))*OW + (2*xx[t]+px))*COUT + co_base+co) = *(float4*)o;
  }
}

// ---------------------------------------------------------------------------
// VQ fused with conv3c 2-partial reduction + bias (round-2 EXACT — FROZEN).
// ---------------------------------------------------------------------------
__global__ __launch_bounds__(256) void vq_k(
    const float* __restrict__ p, const float* __restrict__ bias,
    const float* __restrict__ cb, float* __restrict__ q, int NLat)
{
  __shared__ float slat[4][128];
  int wave = threadIdx.x >> 6;
  int lane = threadIdx.x & 63;
  int l = blockIdx.x*4 + wave;
  if (l >= NLat) return;
  const float* p0 = p + (size_t)l*128;
  const float* p1 = p0 + (size_t)NLat*128;
  slat[wave][lane]    = p0[lane]    + p1[lane]    + bias[lane];
  slat[wave][lane+64] = p0[lane+64] + p1[lane+64] + bias[lane+64];

  float bestd = INFINITY; int besti = 0;
  for (int c0=0;c0<256;c0+=64){
    int c = c0 + lane;
    const float* cp = cb + (size_t)c*128;
    float d = 0.f;
#pragma unroll 8
    for (int k=0;k<128;k+=4){
      float4 cv = *reinterpret_cast<const float4*>(cp+k);
      float d0 = slat[wave][k+0]-cv.x;
      float d1 = slat[wave][k+1]-cv.y;
      float d2 = slat[wave][k+2]-cv.z;
      float d3 = slat[wave][k+3]-cv.w;
      d += d0*d0; d += d1*d1; d += d2*d2; d += d3*d3;
    }
    if (d < bestd) { bestd = d; besti = c; }
  }
  for (int off=32; off; off>>=1){
    float od = __shfl_down(bestd, off);
    int   oi = __shfl_down(besti, off);
    if (od < bestd || (od == bestd && oi < besti)) { bestd=od; besti=oi; }
  }
  besti = __shfl(besti, 0);
  const float* cp = cb + (size_t)besti*128;
  float* qp = q + (size_t)l*128;
  qp[lane]    = cp[lane];
  qp[lane+64] = cp[lane+64];
}

// ---------------------------------------------------------------------------
// Final 3x3 conv 32->3, r2-EXACT direct form (512 blocks, bias-init, writes
// d_out). r2 ran this exact kernel with identical absmax — zero risk.
// ---------------------------------------------------------------------------
__global__ __launch_bounds__(256) void conv_last_k(
    const float* __restrict__ in, const float* __restrict__ w,
    const float* __restrict__ bias, float* __restrict__ out,
    int N,int H,int W)
{
  int p = blockIdx.x*256 + threadIdx.x;
  int total = N*H*W;
  if (p>=total) return;
  int x = p % W; int r = p / W; int y = r % H; int n = r / H;
  float a0=bias[0], a1=bias[1], a2=bias[2];
  const float* base = in + (size_t)n*H*W*32;
  for (int ky=0;ky<3;ky++){ int iy=y+ky-1; if(iy<0||iy>=H) continue;
    for (int kx=0;kx<3;kx++){ int ix=x+kx-1; if(ix<0||ix>=W) continue;
      const float* ip = base + (size_t)(iy*W+ix)*32;
      const float* wp = w + (size_t)((ky*3+kx)*32)*3;
#pragma unroll
      for (int ci=0;ci<32;ci+=4){
        float va[4]; *(float4*)va = *(const float4*)(ip+ci);
        float wv[12];
        *(float4*)(wv+0) = *(const float4*)(wp+ci*3+0);
        *(float4*)(wv+4) = *(const float4*)(wp+ci*3+4);
        *(float4*)(wv+8) = *(const float4*)(wp+ci*3+8);
#pragma unroll
        for (int r2=0;r2<4;r2++){
          a0 = fmaf(va[r2], wv[r2*3+0], a0);
          a1 = fmaf(va[r2], wv[r2*3+1], a1);
          a2 = fmaf(va[r2], wv[r2*3+2], a2);
        }
      }
    }
  }
  out[(size_t)p*3+0]=a0; out[(size_t)p*3+1]=a1; out[(size_t)p*3+2]=a2;
}

extern "C" void kernel_launch(void* const* d_in, const int* in_sizes, int n_in,
                              void* d_out, int out_size, void* d_ws, size_t ws_size,
                              hipStream_t stream) {
  const float* x    = (const float*)d_in[0];
  const float* k1   = (const float*)d_in[1];  const float* b1  = (const float*)d_in[2];
  const float* k1c  = (const float*)d_in[3];  const float* b1c = (const float*)d_in[4];
  const float* k2   = (const float*)d_in[5];  const float* b2  = (const float*)d_in[6];
  const float* k2c  = (const float*)d_in[7];  const float* b2c = (const float*)d_in[8];
  const float* k3   = (const float*)d_in[9];  const float* b3  = (const float*)d_in[10];
  const float* k3c  = (const float*)d_in[11]; const float* b3c = (const float*)d_in[12];
  const float* cb   = (const float*)d_in[13];
  const float* tk1  = (const float*)d_in[14]; const float* tb1  = (const float*)d_in[15];
  const float* tk1c = (const float*)d_in[16]; const float* tb1c = (const float*)d_in[17];
  const float* tk2  = (const float*)d_in[18]; const float* tb2  = (const float*)d_in[19];
  const float* tk2c = (const float*)d_in[20]; const float* tb2c = (const float*)d_in[21];
  const float* tk3  = (const float*)d_in[22]; const float* tb3  = (const float*)d_in[23];
  const float* tk3c = (const float*)d_in[24]; const float* tb3c = (const float*)d_in[25];
  float* out = (float*)d_out;

  float* S  = (float*)d_ws;
  float* W0 = S;                 // [0 .. 1M) floats
  float* W1 = S + 1048576;       // [1M .. 2M)
  float* PA = S + 2097152;       // conv2 partials   [2M..3M)
  float* PB = S + 3145728;       // conv3 partials   [3M..4M)
  float* PC = S + 2097152;       // conv3c partials  [2M..2.5M)
  float* PD = S + 2097152;       // tconv1 partials  [2M..4M)
  float* PE = S + 4194304;       // tk1c partials    [4M..5M)
  float* PF = S + 2097152;       // tconv2 partials  [2M..4M)
  float* PG = S + 2097152;       // tconv3 output    [2M..6M)
  dim3 blk(256);

  // ---- encoder: G-splits + fmaf/reduce order FROZEN (VQ argmin) ----
  conv_k<11,11,2,4,  3, 32,2,true ,true ,1,2,64,0><<< 512,blk,0,stream>>>(x,  k1,  b1,  W0, nullptr,0, 8,128,128,64,64);
  conv_k< 3, 3,1,1, 32, 32,2,true ,true ,1,2,64,0><<< 512,blk,0,stream>>>(W0, k1c, b1c, W1, nullptr,0, 8,64,64,64,64);
  conv_k<11,11,2,4, 32, 64,2,false,false,2,2,32,0><<< 512,blk,0,stream>>>(W1, k2,  nullptr, PA, nullptr,0, 8,64,64,32,32);
  conv_k< 3, 3,1,1, 64, 64,1,true ,true ,1,2,32,2><<< 512,blk,0,stream>>>(PA, k2c, b2c, W0, b2,524288, 8,32,32,32,32);
  conv_k<11,11,2,4, 64,128,2,false,false,4,4,16,0><<< 512,blk,0,stream>>>(W0, k3,  nullptr, PB, nullptr,0, 8,32,32,16,16);
  conv_k< 3, 3,1,1,128,128,1,false,false,2,4,16,4><<< 512,blk,0,stream>>>(PB, k3c, nullptr, PC, b3,262144, 8,16,16,16,16);
  // ---- VQ (FROZEN; reads conv3c partials) ----
  vq_k<<<512,blk,0,stream>>>(PC, b3c, cb, W1, 2048);
  // ---- decoder ----
  tconv_rb<128,64,1,4,2,16,false,0><<<2048,blk,0,stream>>>(W1, tk1, nullptr, PD, nullptr,0, 8,16,16,32,32);
  conv_k< 3, 3,1,1, 64, 64,2,false,false,2,4,32,4><<< 512,blk,0,stream>>>(PD, tk1c, nullptr, PE, tb1,524288, 8,32,32,32,32);
  tconv_rb< 64,32,1,2,1,32,false,2><<<2048,blk,0,stream>>>(PE, tk2, nullptr, PF, tb1c,524288, 8,32,32,64,64);
  conv_k< 3, 3,1,1, 32, 32,2,true ,true ,1,2,64,2><<< 512,blk,0,stream>>>(PF, tk2c, tb2c, W1, tb2,1048576, 8,64,64,64,64);
  tconv_rb< 32,32,1,1,2,64,true ,0><<<4096,blk,0,stream>>>(W1, tk3, tb3, PG, nullptr,0, 8,64,64,128,128);
  // conv_last: r2-exact direct (512 blocks, writes d_out)
  conv_last_k<<<512,blk,0,stream>>>(PG, tk3c, tb3c, out, 8,128,128);
}